// Round 9
// baseline (2580.834 us; speedup 1.0000x reference)
//
#include <hip/hip_runtime.h>
#include <math.h>

// ---------------------------------------------------------------------------
// STU forward, frequency-domain fold:
//   G[w] = sum_k Ffpos[k,w]*Mpos_k + Ffneg[k,w]*Mneg_k + Mdir
//   spec = irfft( rfft(h) @ G[w] )[:, :L, :]
// Layer: h1 = LN(h + spec + Mdir_b); h = LN(h1 + MLP(h1)).
// R7/R8/R9: G stored bf16 (packed re,im in uint) + apply_g reads G once
//        (grid.y splits n, not batch). MLP bf16 MFMA as R6 (passed).
// R9 = R8 resubmit (GPU acquisition timeout; experiment still unmeasured).
// ---------------------------------------------------------------------------

#define LSEQ 2048
#define NFFT 4096
#define NBINS 2049
#define DMODEL 256
#define NK 16
#define NB 8
#define MROWS 16384
#define CHUNKMAX 128

typedef __attribute__((ext_vector_type(8))) short bf16x8;
typedef __attribute__((ext_vector_type(4))) float f32x4;
typedef __attribute__((ext_vector_type(4))) unsigned short ushort4v;

__device__ __forceinline__ float2 cmul(float2 a, float2 b) {
    return make_float2(a.x * b.x - a.y * b.y, a.x * b.y + a.y * b.x);
}

__device__ __forceinline__ unsigned short f2bf(float x) {
    union { float f; unsigned u; } v; v.f = x;
    unsigned r = v.u + 0x7fffu + ((v.u >> 16) & 1u);
    return (unsigned short)(r >> 16);
}

__device__ __forceinline__ float bf2f(unsigned short u) {
    union { unsigned u; float f; } v; v.u = ((unsigned)u) << 16;
    return v.f;
}

// ---------------- Stockham radix-4 FFT core (N=4096, 256 threads) ----------
__device__ __forceinline__ void fft_core(float2* ping, float2* pong, int tid, float sgn) {
    float2* src = ping;
    float2* dst = pong;
    int Ns = 1;
#pragma unroll
    for (int st = 0; st < 6; ++st) {
        __syncthreads();
        float base = sgn * 6.28318530717958647692f / (float)(4 * Ns);
#pragma unroll
        for (int q = 0; q < 4; ++q) {
            int j = tid + (q << 8);
            float2 v0 = src[j];
            float2 v1 = src[j + 1024];
            float2 v2 = src[j + 2048];
            float2 v3 = src[j + 3072];
            int jm = j & (Ns - 1);
            float ang = base * (float)jm;
            float s1, c1;
            __sincosf(ang, &s1, &c1);
            float2 w1 = make_float2(c1, s1);
            float2 w2 = cmul(w1, w1);
            float2 w3 = cmul(w2, w1);
            v1 = cmul(v1, w1);
            v2 = cmul(v2, w2);
            v3 = cmul(v3, w3);
            float2 t0 = make_float2(v0.x + v2.x, v0.y + v2.y);
            float2 t1 = make_float2(v0.x - v2.x, v0.y - v2.y);
            float2 t2 = make_float2(v1.x + v3.x, v1.y + v3.y);
            float2 t3 = make_float2(v1.x - v3.x, v1.y - v3.y);
            float2 y0 = make_float2(t0.x + t2.x, t0.y + t2.y);
            float2 y2 = make_float2(t0.x - t2.x, t0.y - t2.y);
            float2 y1 = make_float2(t1.x - sgn * t3.y, t1.y + sgn * t3.x);
            float2 y3 = make_float2(t1.x + sgn * t3.y, t1.y - sgn * t3.x);
            int idxD = ((j & ~(Ns - 1)) << 2) + jm;
            dst[idxD] = y0;
            dst[idxD + Ns] = y1;
            dst[idxD + 2 * Ns] = y2;
            dst[idxD + 3 * Ns] = y3;
        }
        float2* t = src; src = dst; dst = t;
        Ns <<= 2;
    }
    __syncthreads();
}

__global__ __launch_bounds__(256) void fft_fwd(const float* __restrict__ in,
                                               float2* __restrict__ out) {
    __shared__ float2 ping[NFFT];
    __shared__ float2 pong[NFFT];
    int tid = threadIdx.x;
    const float* ip = in + (size_t)blockIdx.x * LSEQ;
    for (int i = tid; i < NFFT; i += 256)
        ping[i] = make_float2(i < LSEQ ? ip[i] : 0.f, 0.f);
    fft_core(ping, pong, tid, -1.f);
    float2* op = out + (size_t)blockIdx.x * NBINS;
    for (int i = tid; i <= 2048; i += 256) op[i] = ping[i];
}

__global__ __launch_bounds__(256) void fft_fwd2(const float* __restrict__ in,
                                                float2* __restrict__ out) {
    __shared__ float2 ping[NFFT];
    __shared__ float2 pong[NFFT];
    int tid = threadIdx.x;
    const float* r0 = in + (size_t)blockIdx.x * 2 * LSEQ;
    const float* r1 = r0 + LSEQ;
    for (int i = tid; i < NFFT; i += 256)
        ping[i] = (i < LSEQ) ? make_float2(r0[i], r1[i]) : make_float2(0.f, 0.f);
    fft_core(ping, pong, tid, -1.f);
    float2* o0 = out + (size_t)blockIdx.x * 2 * NBINS;
    float2* o1 = o0 + NBINS;
    for (int w = tid; w <= 2048; w += 256) {
        float2 A = ping[w];
        float2 Bc = ping[(NFFT - w) & (NFFT - 1)];
        Bc.y = -Bc.y;
        o0[w] = make_float2(0.5f * (A.x + Bc.x), 0.5f * (A.y + Bc.y));
        float px = A.x - Bc.x, py = A.y - Bc.y;
        o1[w] = make_float2(0.5f * py, -0.5f * px);
    }
}

__global__ __launch_bounds__(256) void fft_inv2(const float2* __restrict__ in,
                                                float* __restrict__ out) {
    __shared__ float2 ping[NFFT];
    __shared__ float2 pong[NFFT];
    int tid = threadIdx.x;
    const float2* W0 = in + (size_t)blockIdx.x * 2 * NBINS;
    const float2* W1 = W0 + NBINS;
    for (int i = tid; i < NFFT; i += 256) {
        float2 v;
        if (i <= 2048) {
            float2 a = W0[i], b = W1[i];
            v = make_float2(a.x - b.y, a.y + b.x);
        } else {
            int m = NFFT - i;
            float2 a = W0[m], b = W1[m];
            v = make_float2(a.x + b.y, b.x - a.y);
        }
        ping[i] = v;
    }
    fft_core(ping, pong, tid, 1.f);
    float* r0 = out + (size_t)blockIdx.x * 2 * LSEQ;
    float* r1 = r0 + LSEQ;
    const float s = 1.f / (float)NFFT;
    for (int i = tid; i < LSEQ; i += 256) {
        r0[i] = ping[i].x * s;
        r1[i] = ping[i].y * s;
    }
}

// ---------------- transposes ------------------------------------------------
__global__ void transpose_f(const float* __restrict__ in, float* __restrict__ out,
                            int R, int C) {
    __shared__ float tile[32][33];
    size_t base = (size_t)blockIdx.z * R * C;
    int c0 = blockIdx.x << 5, r0 = blockIdx.y << 5;
    int tx = threadIdx.x;
    for (int i = threadIdx.y; i < 32; i += 8) {
        int r = r0 + i, c = c0 + tx;
        if (r < R && c < C) tile[i][tx] = in[base + (size_t)r * C + c];
    }
    __syncthreads();
    for (int i = threadIdx.y; i < 32; i += 8) {
        int c = c0 + i, r = r0 + tx;
        if (r < R && c < C) out[base + (size_t)c * R + r] = tile[tx][i];
    }
}

__global__ void transpose_f2(const float2* __restrict__ in, float2* __restrict__ out,
                             int R, int C) {
    __shared__ float2 tile[32][33];
    size_t base = (size_t)blockIdx.z * R * C;
    int c0 = blockIdx.x << 5, r0 = blockIdx.y << 5;
    int tx = threadIdx.x;
    for (int i = threadIdx.y; i < 32; i += 8) {
        int r = r0 + i, c = c0 + tx;
        if (r < R && c < C) tile[i][tx] = in[base + (size_t)r * C + c];
    }
    __syncthreads();
    for (int i = threadIdx.y; i < 32; i += 8) {
        int c = c0 + i, r = r0 + tx;
        if (r < R && c < C) out[base + (size_t)c * R + r] = tile[tx][i];
    }
}

// transpose + f32->bf16: in [R][C] f32 -> out [C][R] bf16
__global__ void transpose_cvt(const float* __restrict__ in, unsigned short* __restrict__ out,
                              int R, int C) {
    __shared__ float tile[32][33];
    int c0 = blockIdx.x << 5, r0 = blockIdx.y << 5;
    int tx = threadIdx.x;
    for (int i = threadIdx.y; i < 32; i += 8) {
        int r = r0 + i, c = c0 + tx;
        if (r < R && c < C) tile[i][tx] = in[(size_t)r * C + c];
    }
    __syncthreads();
    for (int i = threadIdx.y; i < 32; i += 8) {
        int c = c0 + i, r = r0 + tx;
        if (r < R && c < C) out[(size_t)c * R + r] = f2bf(tile[tx][i]);
    }
}

// ---------------- filter prep ----------------------------------------------
__global__ void fneg_kernel(const float* __restrict__ f, float* __restrict__ fn) {
    int i = blockIdx.x * 256 + threadIdx.x;
    if (i < NK * LSEQ) fn[i] = f[i] * ((i & 1) ? -1.f : 1.f);
}

__global__ void pack_kernel(const float2* __restrict__ Ffp, const float2* __restrict__ Ffn,
                            float2* __restrict__ Fpk) {
    int idx = blockIdx.x * 256 + threadIdx.x;
    if (idx >= NBINS * 32) return;
    int w = idx >> 5, kk = idx & 31;
    Fpk[idx] = (kk < 16) ? Ffp[kk * NBINS + w] : Ffn[(kk - 16) * NBINS + w];
}

// ---------------- G build: f32 math, bf16 packed store ---------------------
// Gb[w_local*65536 + c], c = d*256+n; uint = (bf16 re) | (bf16 im)<<16
__global__ __launch_bounds__(256) void build_g(const float* __restrict__ Mpos,
                                               const float* __restrict__ Mneg,
                                               const float* __restrict__ Mdir,
                                               const float2* __restrict__ Fpk,
                                               unsigned int* __restrict__ Gb,
                                               int w0, int CB) {
    __shared__ float2 Fl[CHUNKMAX * 32];
    int tid = threadIdx.x;
    int c = (blockIdx.x << 8) + tid;
    int half = (CB + 1) >> 1;
    int wsrt = blockIdx.y * half;
    int wend = wsrt + half; if (wend > CB) wend = CB;
    for (int i = tid; i < CB * 32; i += 256) Fl[i] = Fpk[w0 * 32 + i];
    float mp[16], mn[16];
#pragma unroll
    for (int k = 0; k < 16; ++k) {
        mp[k] = Mpos[k * 65536 + c];
        mn[k] = Mneg[k * 65536 + c];
    }
    float md = Mdir[c];
    __syncthreads();
    for (int w = wsrt; w < wend; ++w) {
        float gre = md, gim = 0.f;
#pragma unroll
        for (int k = 0; k < 16; ++k) {
            float2 f = Fl[(w << 5) + k];
            float2 fn = Fl[(w << 5) + 16 + k];
            gre = fmaf(f.x, mp[k], gre);
            gim = fmaf(f.y, mp[k], gim);
            gre = fmaf(fn.x, mn[k], gre);
            gim = fmaf(fn.y, mn[k], gim);
        }
        Gb[((size_t)w << 16) + c] = (unsigned)f2bf(gre) | ((unsigned)f2bf(gim) << 16);
    }
}

// ---------------- apply G: Wf[b,w,n] = sum_d Xf[b,w,d]*G[w,d,n] ------------
// grid (CB, 2): y splits n into halves of 128 -> G read exactly once total.
// 256 threads: lane = tid&127 -> n; (tid>>7)*4 -> batch quad.
__global__ __launch_bounds__(256) void apply_g(const float2* __restrict__ Xf,
                                               const unsigned int* __restrict__ Gb,
                                               float2* __restrict__ Wf, int w0) {
    __shared__ float2 Xl[NB * DMODEL];   // 16 KB
    int tid = threadIdx.x;
    int w = w0 + blockIdx.x;
    for (int i = tid; i < NB * DMODEL; i += 256) {
        int b = i >> 8, d = i & 255;
        Xl[i] = Xf[((size_t)b * NBINS + w) * DMODEL + d];
    }
    __syncthreads();
    int n = (blockIdx.y << 7) + (tid & 127);
    int bq = (tid >> 7) << 2;              // 0 or 4
    float2 acc[4] = {};
    const unsigned int* Gp = Gb + ((size_t)blockIdx.x << 16) + n;
#pragma unroll 4
    for (int d = 0; d < DMODEL; ++d) {
        unsigned int gv = Gp[(size_t)d << 8];
        float gre = bf2f((unsigned short)(gv & 0xffffu));
        float gim = bf2f((unsigned short)(gv >> 16));
#pragma unroll
        for (int q = 0; q < 4; ++q) {
            float2 x = Xl[((bq + q) << 8) + d];
            acc[q].x = fmaf(x.x, gre, acc[q].x);
            acc[q].x = fmaf(-x.y, gim, acc[q].x);
            acc[q].y = fmaf(x.x, gim, acc[q].y);
            acc[q].y = fmaf(x.y, gre, acc[q].y);
        }
    }
#pragma unroll
    for (int q = 0; q < 4; ++q)
        Wf[((size_t)(bq + q) * NBINS + w) * DMODEL + n] = acc[q];
}

// ---------------- f32 SGEMM (kept for W_in / W_out projections) ------------
template <int BM, int BN, int SILU>
__global__ __launch_bounds__(256) void sgemm(const float* __restrict__ A,
                                             const float* __restrict__ Bm,
                                             const float* __restrict__ bias,
                                             float* __restrict__ C, int N, int K) {
    constexpr int TM = BM / 16, TN = BN / 16;
    constexpr int LDA = BM + 4;
    __shared__ float As[32 * LDA];
    __shared__ float Bs[32 * BN];
    int tid = threadIdx.x;
    int tx = tid & 15, ty = tid >> 4;
    int m0 = blockIdx.y * BM, n0 = blockIdx.x * BN;
    float acc[TM][TN] = {};

    for (int k0 = 0; k0 < K; k0 += 32) {
#pragma unroll
        for (int r = 0; r < BM / 32; ++r) {
            int id = tid + (r << 8);
            int m = id >> 3, kq = (id & 7) << 2;
            float4 v = *(const float4*)(A + (size_t)(m0 + m) * K + k0 + kq);
            As[(kq + 0) * LDA + m] = v.x;
            As[(kq + 1) * LDA + m] = v.y;
            As[(kq + 2) * LDA + m] = v.z;
            As[(kq + 3) * LDA + m] = v.w;
        }
#pragma unroll
        for (int r = 0; r < BN / 32; ++r) {
            int id = tid + (r << 8);
            int k = id / (BN / 4), c4 = (id % (BN / 4)) << 2;
            *(float4*)(&Bs[k * BN + c4]) =
                *(const float4*)(Bm + (size_t)(k0 + k) * N + n0 + c4);
        }
        __syncthreads();
#pragma unroll
        for (int kk = 0; kk < 32; ++kk) {
            float a[TM], b[TN];
#pragma unroll
            for (int i = 0; i < TM; ++i) a[i] = As[kk * LDA + ty * TM + i];
#pragma unroll
            for (int j = 0; j < TN; ++j) b[j] = Bs[kk * BN + tx * TN + j];
#pragma unroll
            for (int i = 0; i < TM; ++i)
#pragma unroll
                for (int j = 0; j < TN; ++j) acc[i][j] = fmaf(a[i], b[j], acc[i][j]);
        }
        __syncthreads();
    }
#pragma unroll
    for (int i = 0; i < TM; ++i) {
        int row = m0 + ty * TM + i;
#pragma unroll
        for (int j = 0; j < TN; ++j) {
            int col = n0 + tx * TN + j;
            float v = acc[i][j] + bias[col];
            if (SILU) v = v / (1.f + __expf(-v));
            C[(size_t)row * N + col] = v;
        }
    }
}

// ---------------- bf16 MFMA GEMM: C = A @ Bt^T + bias [; silu] -------------
template <int SILU, int OUT_BF16>
__global__ __launch_bounds__(256) void gemm_bf16(const unsigned short* __restrict__ A,
                                                 const unsigned short* __restrict__ Bt,
                                                 const float* __restrict__ bias,
                                                 void* __restrict__ Cout, int N, int K) {
    constexpr int LDT = 40;  // 32 + 8 pad (bf16 elems)
    __shared__ unsigned short As[128 * LDT];
    __shared__ unsigned short Bs[128 * LDT];
    int tid = threadIdx.x;
    int m0 = blockIdx.y << 7, n0 = blockIdx.x << 7;
    int wid = tid >> 6, lane = tid & 63;
    int wr = (wid >> 1) << 6;
    int wc = (wid & 1) << 6;
    int lr = lane & 15;
    int lk = (lane >> 4) << 3;

    f32x4 acc[4][4];
#pragma unroll
    for (int i = 0; i < 4; ++i)
#pragma unroll
        for (int j = 0; j < 4; ++j) acc[i][j] = (f32x4){0.f, 0.f, 0.f, 0.f};

    for (int k0 = 0; k0 < K; k0 += 32) {
#pragma unroll
        for (int q = 0; q < 2; ++q) {
            int c = (tid << 1) + q;
            int m = c >> 2, ko = (c & 3) << 3;
            *(bf16x8*)&As[m * LDT + ko] =
                *(const bf16x8*)&A[(size_t)(m0 + m) * K + k0 + ko];
            *(bf16x8*)&Bs[m * LDT + ko] =
                *(const bf16x8*)&Bt[(size_t)(n0 + m) * K + k0 + ko];
        }
        __syncthreads();
        bf16x8 af[4], bfr[4];
#pragma unroll
        for (int i = 0; i < 4; ++i)
            af[i] = *(const bf16x8*)&As[(wr + i * 16 + lr) * LDT + lk];
#pragma unroll
        for (int j = 0; j < 4; ++j)
            bfr[j] = *(const bf16x8*)&Bs[(wc + j * 16 + lr) * LDT + lk];
#pragma unroll
        for (int i = 0; i < 4; ++i)
#pragma unroll
            for (int j = 0; j < 4; ++j)
                acc[i][j] = __builtin_amdgcn_mfma_f32_16x16x32_bf16(af[i], bfr[j],
                                                                    acc[i][j], 0, 0, 0);
        __syncthreads();
    }
    int rbase = (lane >> 4) << 2;
#pragma unroll
    for (int i = 0; i < 4; ++i) {
#pragma unroll
        for (int j = 0; j < 4; ++j) {
            int col = n0 + wc + j * 16 + lr;
            float bv = bias[col];
#pragma unroll
            for (int r = 0; r < 4; ++r) {
                int row = m0 + wr + i * 16 + rbase + r;
                float v = acc[i][j][r] + bv;
                if (SILU) v = v / (1.f + __expf(-v));
                if (OUT_BF16)
                    ((unsigned short*)Cout)[(size_t)row * N + col] = f2bf(v);
                else
                    ((float*)Cout)[(size_t)row * N + col] = v;
            }
        }
    }
}

// ---------------- LayerNorm (+ optional bf16 copy of output) ---------------
__global__ __launch_bounds__(256) void ln_kernel(const float* __restrict__ x1,
                                                 const float* __restrict__ x2,
                                                 const float* __restrict__ cbias,
                                                 const float* __restrict__ g,
                                                 const float* __restrict__ bt,
                                                 float* __restrict__ out,
                                                 unsigned short* __restrict__ out_bf) {
    int lane = threadIdx.x & 63;
    size_t row = ((size_t)blockIdx.x << 2) + (threadIdx.x >> 6);
    int c = lane << 2;
    size_t off = row * DMODEL + c;
    float4 x = *(const float4*)(x1 + off);
    float4 y = *(const float4*)(x2 + off);
    x.x += y.x; x.y += y.y; x.z += y.z; x.w += y.w;
    if (cbias) {
        float4 cb = *(const float4*)(cbias + c);
        x.x += cb.x; x.y += cb.y; x.z += cb.z; x.w += cb.w;
    }
    float s = x.x + x.y + x.z + x.w;
    float sq = x.x * x.x + x.y * x.y + x.z * x.z + x.w * x.w;
#pragma unroll
    for (int m = 32; m; m >>= 1) {
        s += __shfl_xor(s, m);
        sq += __shfl_xor(sq, m);
    }
    float mean = s * (1.f / 256.f);
    float var = sq * (1.f / 256.f) - mean * mean;
    float rinv = rsqrtf(var + 1e-5f);
    float4 gg = *(const float4*)(g + c);
    float4 bb = *(const float4*)(bt + c);
    float4 o;
    o.x = (x.x - mean) * rinv * gg.x + bb.x;
    o.y = (x.y - mean) * rinv * gg.y + bb.y;
    o.z = (x.z - mean) * rinv * gg.z + bb.z;
    o.w = (x.w - mean) * rinv * gg.w + bb.w;
    *(float4*)(out + off) = o;
    if (out_bf) {
        ushort4v ob;
        ob.x = f2bf(o.x); ob.y = f2bf(o.y); ob.z = f2bf(o.z); ob.w = f2bf(o.w);
        *(ushort4v*)(out_bf + off) = ob;
    }
}

// ---------------------------------------------------------------------------
extern "C" void kernel_launch(void* const* d_in, const int* in_sizes, int n_in,
                              void* d_out, int out_size, void* d_ws, size_t ws_size,
                              hipStream_t stream) {
    const float* obs     = (const float*)d_in[0];
    const float* filters = (const float*)d_in[1];
    const float* W_in    = (const float*)d_in[2];
    const float* b_in    = (const float*)d_in[3];
    const float* Mpos    = (const float*)d_in[4];
    const float* Mneg    = (const float*)d_in[5];
    const float* MdirW   = (const float*)d_in[6];
    const float* Mdirb   = (const float*)d_in[7];
    const float* ln1g    = (const float*)d_in[8];
    const float* ln1b    = (const float*)d_in[9];
    const float* W1      = (const float*)d_in[10];
    const float* b1      = (const float*)d_in[11];
    const float* W2      = (const float*)d_in[12];
    const float* b2      = (const float*)d_in[13];
    const float* ln2g    = (const float*)d_in[14];
    const float* ln2b    = (const float*)d_in[15];
    const float* W_out   = (const float*)d_in[16];
    const float* b_out   = (const float*)d_in[17];
    float* out = (float*)d_out;

    // ---- workspace (floats), liveness-aliased ----
    float* p = (float*)d_ws;
    float* h   = p; p += 4194304;       // (B,L,D)
    float* C1  = p; p += 8392704;       // XfT -> Wf -> spec (first 4.2M) | bf16 tail
    float* C2  = p; p += 8392704;       // Xf -> WfT -> hln
    float* Ffp = p; p += 65568;
    float* Ffn = p; p += 65568;
    float* Fpk = p; p += 131136;
    float* fng = p; p += 32768;
    float* big = p;
    size_t fixed_f = (size_t)(big - (float*)d_ws);
    size_t avail_f = (ws_size / 4 > fixed_f) ? ws_size / 4 - fixed_f : 0;

    int chunk = CHUNKMAX;                              // Gb: chunk*65536 uints
    while (chunk > 8 && (size_t)chunk * 65536 > avail_f) chunk >>= 1;
    int RB = 16384;                                    // MLP row block
    while (RB > 128 && (size_t)RB * 512 > avail_f) RB >>= 1;   // mid_bf = RB*512 f32

    float* sT  = big;
    unsigned int* Gb = (unsigned int*)big;
    unsigned short* mid_bf = (unsigned short*)big;
    // bf16 side buffers live in C1's tail (spec only uses C1[0 .. 4.2M))
    unsigned short* hln_bf = (unsigned short*)(C1 + 4194304);   // 2,097,152 f32
    unsigned short* W1T    = (unsigned short*)(C1 + 6291456);   // 131,072 f32
    unsigned short* W2T    = (unsigned short*)(C1 + 6422528);   // 131,072 f32

    dim3 tb(32, 8);

    // filter prep
    fneg_kernel<<<128, 256, 0, stream>>>(filters, fng);
    fft_fwd<<<NK, 256, 0, stream>>>(filters, (float2*)Ffp);
    fft_fwd<<<NK, 256, 0, stream>>>(fng, (float2*)Ffn);
    pack_kernel<<<(NBINS * 32 + 255) / 256, 256, 0, stream>>>((float2*)Ffp, (float2*)Ffn,
                                                              (float2*)Fpk);
    // input projection: h = obs @ W_in + b_in
    sgemm<128, 64, 0><<<dim3(4, 128), 256, 0, stream>>>(obs, W_in, b_in, h, 256, 128);

    for (int i = 0; i < 2; ++i) {
        const float* Mp = Mpos + (size_t)i * 1048576;
        const float* Mn = Mneg + (size_t)i * 1048576;
        const float* Md = MdirW + (size_t)i * 65536;

        // h (B,L,D) -> sT (B,D,L); packed FFT -> C1; -> C2 = Xf (B,2049,D)
        transpose_f<<<dim3(8, 64, 8), tb, 0, stream>>>(h, sT, LSEQ, DMODEL);
        fft_fwd2<<<1024, 256, 0, stream>>>(sT, (float2*)C1);
        transpose_f2<<<dim3(65, 8, 8), tb, 0, stream>>>((float2*)C1, (float2*)C2,
                                                        DMODEL, NBINS);
        // chunked G build (bf16) + apply (Wf -> C1)
        for (int w0 = 0; w0 < NBINS; w0 += chunk) {
            int CB = (NBINS - w0 < chunk) ? (NBINS - w0) : chunk;
            build_g<<<dim3(256, 2), 256, 0, stream>>>(Mp, Mn, Md, (float2*)Fpk,
                                                      Gb, w0, CB);
            apply_g<<<dim3(CB, 2), 256, 0, stream>>>((float2*)C2, Gb,
                                                     (float2*)C1, w0);
        }
        // Wf (C1) -> WfT (C2); packed iFFT -> sT; -> spec (C1[0..4.2M))
        transpose_f2<<<dim3(8, 65, 8), tb, 0, stream>>>((float2*)C1, (float2*)C2,
                                                        NBINS, DMODEL);
        fft_inv2<<<1024, 256, 0, stream>>>((float2*)C2, sT);
        transpose_f<<<dim3(64, 8, 8), tb, 0, stream>>>(sT, C1, DMODEL, LSEQ);

        float* spec = C1;   // (B,L,D)
        float* hln  = C2;   // (B,L,D)

        // LN1: hln = LN(h + spec + Mdir_b); also write bf16 copy
        ln_kernel<<<4096, 256, 0, stream>>>(h, spec, Mdirb + i * 256, ln1g + i * 256,
                                            ln1b + i * 256, hln, hln_bf);
        // weights -> bf16 transposed
        transpose_cvt<<<dim3(32, 8), tb, 0, stream>>>(W1 + (size_t)i * 262144, W1T,
                                                      256, 1024);
        transpose_cvt<<<dim3(8, 32), tb, 0, stream>>>(W2 + (size_t)i * 262144, W2T,
                                                      1024, 256);
        // MLP (bf16 MFMA): mid = silu(hln@W1+b1) [bf16]; mlpout = mid@W2+b2 [f32]
        for (int r0 = 0; r0 < MROWS; r0 += RB) {
            int rb = (MROWS - r0 < RB) ? (MROWS - r0) : RB;
            gemm_bf16<1, 1><<<dim3(8, rb / 128), 256, 0, stream>>>(
                hln_bf + (size_t)r0 * 256, W1T, b1 + i * 1024, mid_bf, 1024, 256);
            gemm_bf16<0, 0><<<dim3(2, rb / 128), 256, 0, stream>>>(
                mid_bf, W2T, b2 + i * 256, spec + (size_t)r0 * 256, 256, 1024);
        }
        // LN2: h = LN(hln + mlpout)
        ln_kernel<<<4096, 256, 0, stream>>>(hln, spec, nullptr, ln2g + i * 256,
                                            ln2b + i * 256, h, nullptr);
    }
    // output projection
    sgemm<64, 32, 0><<<dim3(1, 256), 256, 0, stream>>>(h, W_out, b_out, out, 32, 256);
}

// Round 12
// 1667.469 us; speedup vs baseline: 1.5478x; 1.5478x over previous
//
#include <hip/hip_runtime.h>
#include <math.h>

// ---------------------------------------------------------------------------
// STU forward, frequency-domain fold:
//   G[w] = sum_k Ffpos[k,w]*Mpos_k + Ffneg[k,w]*Mneg_k + Mdir
//   spec = irfft( rfft(h) @ G[w] )[:, :L, :]
// Layer: h1 = LN(h + spec + Mdir_b); h = LN(h1 + MLP(h1)).
// R10-R12: build_g was latency-bound (42% VALU, 15% occ, 1.38 ms total).
//      -> grid.y=8 w-split (8 blocks/CU), per-block 8KB filter slice,
//         2-way w ILP (4 indep fmaf chains), CHUNKMAX 256.
// R12 = third submit of this experiment (two GPU-acquisition timeouts).
// ---------------------------------------------------------------------------

#define LSEQ 2048
#define NFFT 4096
#define NBINS 2049
#define DMODEL 256
#define NK 16
#define NB 8
#define MROWS 16384
#define CHUNKMAX 256
#define NSPLIT 8

typedef __attribute__((ext_vector_type(8))) short bf16x8;
typedef __attribute__((ext_vector_type(4))) float f32x4;
typedef __attribute__((ext_vector_type(4))) unsigned short ushort4v;

__device__ __forceinline__ float2 cmul(float2 a, float2 b) {
    return make_float2(a.x * b.x - a.y * b.y, a.x * b.y + a.y * b.x);
}

__device__ __forceinline__ unsigned short f2bf(float x) {
    union { float f; unsigned u; } v; v.f = x;
    unsigned r = v.u + 0x7fffu + ((v.u >> 16) & 1u);
    return (unsigned short)(r >> 16);
}

__device__ __forceinline__ float bf2f(unsigned short u) {
    union { unsigned u; float f; } v; v.u = ((unsigned)u) << 16;
    return v.f;
}

// ---------------- Stockham radix-4 FFT core (N=4096, 256 threads) ----------
__device__ __forceinline__ void fft_core(float2* ping, float2* pong, int tid, float sgn) {
    float2* src = ping;
    float2* dst = pong;
    int Ns = 1;
#pragma unroll
    for (int st = 0; st < 6; ++st) {
        __syncthreads();
        float base = sgn * 6.28318530717958647692f / (float)(4 * Ns);
#pragma unroll
        for (int q = 0; q < 4; ++q) {
            int j = tid + (q << 8);
            float2 v0 = src[j];
            float2 v1 = src[j + 1024];
            float2 v2 = src[j + 2048];
            float2 v3 = src[j + 3072];
            int jm = j & (Ns - 1);
            float ang = base * (float)jm;
            float s1, c1;
            __sincosf(ang, &s1, &c1);
            float2 w1 = make_float2(c1, s1);
            float2 w2 = cmul(w1, w1);
            float2 w3 = cmul(w2, w1);
            v1 = cmul(v1, w1);
            v2 = cmul(v2, w2);
            v3 = cmul(v3, w3);
            float2 t0 = make_float2(v0.x + v2.x, v0.y + v2.y);
            float2 t1 = make_float2(v0.x - v2.x, v0.y - v2.y);
            float2 t2 = make_float2(v1.x + v3.x, v1.y + v3.y);
            float2 t3 = make_float2(v1.x - v3.x, v1.y - v3.y);
            float2 y0 = make_float2(t0.x + t2.x, t0.y + t2.y);
            float2 y2 = make_float2(t0.x - t2.x, t0.y - t2.y);
            float2 y1 = make_float2(t1.x - sgn * t3.y, t1.y + sgn * t3.x);
            float2 y3 = make_float2(t1.x + sgn * t3.y, t1.y - sgn * t3.x);
            int idxD = ((j & ~(Ns - 1)) << 2) + jm;
            dst[idxD] = y0;
            dst[idxD + Ns] = y1;
            dst[idxD + 2 * Ns] = y2;
            dst[idxD + 3 * Ns] = y3;
        }
        float2* t = src; src = dst; dst = t;
        Ns <<= 2;
    }
    __syncthreads();
}

__global__ __launch_bounds__(256) void fft_fwd(const float* __restrict__ in,
                                               float2* __restrict__ out) {
    __shared__ float2 ping[NFFT];
    __shared__ float2 pong[NFFT];
    int tid = threadIdx.x;
    const float* ip = in + (size_t)blockIdx.x * LSEQ;
    for (int i = tid; i < NFFT; i += 256)
        ping[i] = make_float2(i < LSEQ ? ip[i] : 0.f, 0.f);
    fft_core(ping, pong, tid, -1.f);
    float2* op = out + (size_t)blockIdx.x * NBINS;
    for (int i = tid; i <= 2048; i += 256) op[i] = ping[i];
}

__global__ __launch_bounds__(256) void fft_fwd2(const float* __restrict__ in,
                                                float2* __restrict__ out) {
    __shared__ float2 ping[NFFT];
    __shared__ float2 pong[NFFT];
    int tid = threadIdx.x;
    const float* r0 = in + (size_t)blockIdx.x * 2 * LSEQ;
    const float* r1 = r0 + LSEQ;
    for (int i = tid; i < NFFT; i += 256)
        ping[i] = (i < LSEQ) ? make_float2(r0[i], r1[i]) : make_float2(0.f, 0.f);
    fft_core(ping, pong, tid, -1.f);
    float2* o0 = out + (size_t)blockIdx.x * 2 * NBINS;
    float2* o1 = o0 + NBINS;
    for (int w = tid; w <= 2048; w += 256) {
        float2 A = ping[w];
        float2 Bc = ping[(NFFT - w) & (NFFT - 1)];
        Bc.y = -Bc.y;
        o0[w] = make_float2(0.5f * (A.x + Bc.x), 0.5f * (A.y + Bc.y));
        float px = A.x - Bc.x, py = A.y - Bc.y;
        o1[w] = make_float2(0.5f * py, -0.5f * px);
    }
}

__global__ __launch_bounds__(256) void fft_inv2(const float2* __restrict__ in,
                                                float* __restrict__ out) {
    __shared__ float2 ping[NFFT];
    __shared__ float2 pong[NFFT];
    int tid = threadIdx.x;
    const float2* W0 = in + (size_t)blockIdx.x * 2 * NBINS;
    const float2* W1 = W0 + NBINS;
    for (int i = tid; i < NFFT; i += 256) {
        float2 v;
        if (i <= 2048) {
            float2 a = W0[i], b = W1[i];
            v = make_float2(a.x - b.y, a.y + b.x);
        } else {
            int m = NFFT - i;
            float2 a = W0[m], b = W1[m];
            v = make_float2(a.x + b.y, b.x - a.y);
        }
        ping[i] = v;
    }
    fft_core(ping, pong, tid, 1.f);
    float* r0 = out + (size_t)blockIdx.x * 2 * LSEQ;
    float* r1 = r0 + LSEQ;
    const float s = 1.f / (float)NFFT;
    for (int i = tid; i < LSEQ; i += 256) {
        r0[i] = ping[i].x * s;
        r1[i] = ping[i].y * s;
    }
}

// ---------------- transposes ------------------------------------------------
__global__ void transpose_f(const float* __restrict__ in, float* __restrict__ out,
                            int R, int C) {
    __shared__ float tile[32][33];
    size_t base = (size_t)blockIdx.z * R * C;
    int c0 = blockIdx.x << 5, r0 = blockIdx.y << 5;
    int tx = threadIdx.x;
    for (int i = threadIdx.y; i < 32; i += 8) {
        int r = r0 + i, c = c0 + tx;
        if (r < R && c < C) tile[i][tx] = in[base + (size_t)r * C + c];
    }
    __syncthreads();
    for (int i = threadIdx.y; i < 32; i += 8) {
        int c = c0 + i, r = r0 + tx;
        if (r < R && c < C) out[base + (size_t)c * R + r] = tile[tx][i];
    }
}

__global__ void transpose_f2(const float2* __restrict__ in, float2* __restrict__ out,
                             int R, int C) {
    __shared__ float2 tile[32][33];
    size_t base = (size_t)blockIdx.z * R * C;
    int c0 = blockIdx.x << 5, r0 = blockIdx.y << 5;
    int tx = threadIdx.x;
    for (int i = threadIdx.y; i < 32; i += 8) {
        int r = r0 + i, c = c0 + tx;
        if (r < R && c < C) tile[i][tx] = in[base + (size_t)r * C + c];
    }
    __syncthreads();
    for (int i = threadIdx.y; i < 32; i += 8) {
        int c = c0 + i, r = r0 + tx;
        if (r < R && c < C) out[base + (size_t)c * R + r] = tile[tx][i];
    }
}

// transpose + f32->bf16: in [R][C] f32 -> out [C][R] bf16
__global__ void transpose_cvt(const float* __restrict__ in, unsigned short* __restrict__ out,
                              int R, int C) {
    __shared__ float tile[32][33];
    int c0 = blockIdx.x << 5, r0 = blockIdx.y << 5;
    int tx = threadIdx.x;
    for (int i = threadIdx.y; i < 32; i += 8) {
        int r = r0 + i, c = c0 + tx;
        if (r < R && c < C) tile[i][tx] = in[(size_t)r * C + c];
    }
    __syncthreads();
    for (int i = threadIdx.y; i < 32; i += 8) {
        int c = c0 + i, r = r0 + tx;
        if (r < R && c < C) out[(size_t)c * R + r] = f2bf(tile[tx][i]);
    }
}

// ---------------- filter prep ----------------------------------------------
__global__ void fneg_kernel(const float* __restrict__ f, float* __restrict__ fn) {
    int i = blockIdx.x * 256 + threadIdx.x;
    if (i < NK * LSEQ) fn[i] = f[i] * ((i & 1) ? -1.f : 1.f);
}

__global__ void pack_kernel(const float2* __restrict__ Ffp, const float2* __restrict__ Ffn,
                            float2* __restrict__ Fpk) {
    int idx = blockIdx.x * 256 + threadIdx.x;
    if (idx >= NBINS * 32) return;
    int w = idx >> 5, kk = idx & 31;
    Fpk[idx] = (kk < 16) ? Ffp[kk * NBINS + w] : Ffn[(kk - 16) * NBINS + w];
}

// ---------------- G build: f32 math, bf16 packed store ---------------------
// grid (256, NSPLIT): block handles w in [wsrt,wend) of chunk; loads only its
// own filter slice (<=8KB LDS). 2-way w ILP -> 4 independent fmaf chains.
__global__ __launch_bounds__(256) void build_g(const float* __restrict__ Mpos,
                                               const float* __restrict__ Mneg,
                                               const float* __restrict__ Mdir,
                                               const float2* __restrict__ Fpk,
                                               unsigned int* __restrict__ Gb,
                                               int w0, int CB) {
    __shared__ float2 Fl[(CHUNKMAX / NSPLIT) * 32];   // 8 KB
    int tid = threadIdx.x;
    int c = (blockIdx.x << 8) + tid;
    int wper = (CB + NSPLIT - 1) / NSPLIT;
    int wsrt = blockIdx.y * wper;
    int wend = wsrt + wper; if (wend > CB) wend = CB;
    int wcount = wend - wsrt;
    if (wcount <= 0) return;
    for (int i = tid; i < wcount * 32; i += 256)
        Fl[i] = Fpk[(w0 + wsrt) * 32 + i];
    float mp[16], mn[16];
#pragma unroll
    for (int k = 0; k < 16; ++k) {
        mp[k] = Mpos[k * 65536 + c];
        mn[k] = Mneg[k * 65536 + c];
    }
    float md = Mdir[c];
    __syncthreads();
    int w = 0;
    for (; w + 2 <= wcount; w += 2) {
        float g0r = md, g0i = 0.f, g1r = md, g1i = 0.f;
#pragma unroll
        for (int k = 0; k < 16; ++k) {
            float2 f0 = Fl[(w << 5) + k];
            float2 n0 = Fl[(w << 5) + 16 + k];
            float2 f1 = Fl[((w + 1) << 5) + k];
            float2 n1 = Fl[((w + 1) << 5) + 16 + k];
            g0r = fmaf(f0.x, mp[k], g0r);
            g0i = fmaf(f0.y, mp[k], g0i);
            g1r = fmaf(f1.x, mp[k], g1r);
            g1i = fmaf(f1.y, mp[k], g1i);
            g0r = fmaf(n0.x, mn[k], g0r);
            g0i = fmaf(n0.y, mn[k], g0i);
            g1r = fmaf(n1.x, mn[k], g1r);
            g1i = fmaf(n1.y, mn[k], g1i);
        }
        Gb[((size_t)(wsrt + w) << 16) + c] =
            (unsigned)f2bf(g0r) | ((unsigned)f2bf(g0i) << 16);
        Gb[((size_t)(wsrt + w + 1) << 16) + c] =
            (unsigned)f2bf(g1r) | ((unsigned)f2bf(g1i) << 16);
    }
    if (w < wcount) {
        float gre = md, gim = 0.f;
#pragma unroll
        for (int k = 0; k < 16; ++k) {
            float2 f = Fl[(w << 5) + k];
            float2 fn = Fl[(w << 5) + 16 + k];
            gre = fmaf(f.x, mp[k], gre);
            gim = fmaf(f.y, mp[k], gim);
            gre = fmaf(fn.x, mn[k], gre);
            gim = fmaf(fn.y, mn[k], gim);
        }
        Gb[((size_t)(wsrt + w) << 16) + c] =
            (unsigned)f2bf(gre) | ((unsigned)f2bf(gim) << 16);
    }
}

// ---------------- apply G: Wf[b,w,n] = sum_d Xf[b,w,d]*G[w,d,n] ------------
// grid (CB, 2): y splits n into halves of 128 -> G read exactly once total.
__global__ __launch_bounds__(256) void apply_g(const float2* __restrict__ Xf,
                                               const unsigned int* __restrict__ Gb,
                                               float2* __restrict__ Wf, int w0) {
    __shared__ float2 Xl[NB * DMODEL];   // 16 KB
    int tid = threadIdx.x;
    int w = w0 + blockIdx.x;
    for (int i = tid; i < NB * DMODEL; i += 256) {
        int b = i >> 8, d = i & 255;
        Xl[i] = Xf[((size_t)b * NBINS + w) * DMODEL + d];
    }
    __syncthreads();
    int n = (blockIdx.y << 7) + (tid & 127);
    int bq = (tid >> 7) << 2;              // 0 or 4
    float2 acc[4] = {};
    const unsigned int* Gp = Gb + ((size_t)blockIdx.x << 16) + n;
#pragma unroll 4
    for (int d = 0; d < DMODEL; ++d) {
        unsigned int gv = Gp[(size_t)d << 8];
        float gre = bf2f((unsigned short)(gv & 0xffffu));
        float gim = bf2f((unsigned short)(gv >> 16));
#pragma unroll
        for (int q = 0; q < 4; ++q) {
            float2 x = Xl[((bq + q) << 8) + d];
            acc[q].x = fmaf(x.x, gre, acc[q].x);
            acc[q].x = fmaf(-x.y, gim, acc[q].x);
            acc[q].y = fmaf(x.x, gim, acc[q].y);
            acc[q].y = fmaf(x.y, gre, acc[q].y);
        }
    }
#pragma unroll
    for (int q = 0; q < 4; ++q)
        Wf[((size_t)(bq + q) * NBINS + w) * DMODEL + n] = acc[q];
}

// ---------------- f32 SGEMM (kept for W_in / W_out projections) ------------
template <int BM, int BN, int SILU>
__global__ __launch_bounds__(256) void sgemm(const float* __restrict__ A,
                                             const float* __restrict__ Bm,
                                             const float* __restrict__ bias,
                                             float* __restrict__ C, int N, int K) {
    constexpr int TM = BM / 16, TN = BN / 16;
    constexpr int LDA = BM + 4;
    __shared__ float As[32 * LDA];
    __shared__ float Bs[32 * BN];
    int tid = threadIdx.x;
    int tx = tid & 15, ty = tid >> 4;
    int m0 = blockIdx.y * BM, n0 = blockIdx.x * BN;
    float acc[TM][TN] = {};

    for (int k0 = 0; k0 < K; k0 += 32) {
#pragma unroll
        for (int r = 0; r < BM / 32; ++r) {
            int id = tid + (r << 8);
            int m = id >> 3, kq = (id & 7) << 2;
            float4 v = *(const float4*)(A + (size_t)(m0 + m) * K + k0 + kq);
            As[(kq + 0) * LDA + m] = v.x;
            As[(kq + 1) * LDA + m] = v.y;
            As[(kq + 2) * LDA + m] = v.z;
            As[(kq + 3) * LDA + m] = v.w;
        }
#pragma unroll
        for (int r = 0; r < BN / 32; ++r) {
            int id = tid + (r << 8);
            int k = id / (BN / 4), c4 = (id % (BN / 4)) << 2;
            *(float4*)(&Bs[k * BN + c4]) =
                *(const float4*)(Bm + (size_t)(k0 + k) * N + n0 + c4);
        }
        __syncthreads();
#pragma unroll
        for (int kk = 0; kk < 32; ++kk) {
            float a[TM], b[TN];
#pragma unroll
            for (int i = 0; i < TM; ++i) a[i] = As[kk * LDA + ty * TM + i];
#pragma unroll
            for (int j = 0; j < TN; ++j) b[j] = Bs[kk * BN + tx * TN + j];
#pragma unroll
            for (int i = 0; i < TM; ++i)
#pragma unroll
                for (int j = 0; j < TN; ++j) acc[i][j] = fmaf(a[i], b[j], acc[i][j]);
        }
        __syncthreads();
    }
#pragma unroll
    for (int i = 0; i < TM; ++i) {
        int row = m0 + ty * TM + i;
#pragma unroll
        for (int j = 0; j < TN; ++j) {
            int col = n0 + tx * TN + j;
            float v = acc[i][j] + bias[col];
            if (SILU) v = v / (1.f + __expf(-v));
            C[(size_t)row * N + col] = v;
        }
    }
}

// ---------------- bf16 MFMA GEMM: C = A @ Bt^T + bias [; silu] -------------
template <int SILU, int OUT_BF16>
__global__ __launch_bounds__(256) void gemm_bf16(const unsigned short* __restrict__ A,
                                                 const unsigned short* __restrict__ Bt,
                                                 const float* __restrict__ bias,
                                                 void* __restrict__ Cout, int N, int K) {
    constexpr int LDT = 40;  // 32 + 8 pad (bf16 elems)
    __shared__ unsigned short As[128 * LDT];
    __shared__ unsigned short Bs[128 * LDT];
    int tid = threadIdx.x;
    int m0 = blockIdx.y << 7, n0 = blockIdx.x << 7;
    int wid = tid >> 6, lane = tid & 63;
    int wr = (wid >> 1) << 6;
    int wc = (wid & 1) << 6;
    int lr = lane & 15;
    int lk = (lane >> 4) << 3;

    f32x4 acc[4][4];
#pragma unroll
    for (int i = 0; i < 4; ++i)
#pragma unroll
        for (int j = 0; j < 4; ++j) acc[i][j] = (f32x4){0.f, 0.f, 0.f, 0.f};

    for (int k0 = 0; k0 < K; k0 += 32) {
#pragma unroll
        for (int q = 0; q < 2; ++q) {
            int c = (tid << 1) + q;
            int m = c >> 2, ko = (c & 3) << 3;
            *(bf16x8*)&As[m * LDT + ko] =
                *(const bf16x8*)&A[(size_t)(m0 + m) * K + k0 + ko];
            *(bf16x8*)&Bs[m * LDT + ko] =
                *(const bf16x8*)&Bt[(size_t)(n0 + m) * K + k0 + ko];
        }
        __syncthreads();
        bf16x8 af[4], bfr[4];
#pragma unroll
        for (int i = 0; i < 4; ++i)
            af[i] = *(const bf16x8*)&As[(wr + i * 16 + lr) * LDT + lk];
#pragma unroll
        for (int j = 0; j < 4; ++j)
            bfr[j] = *(const bf16x8*)&Bs[(wc + j * 16 + lr) * LDT + lk];
#pragma unroll
        for (int i = 0; i < 4; ++i)
#pragma unroll
            for (int j = 0; j < 4; ++j)
                acc[i][j] = __builtin_amdgcn_mfma_f32_16x16x32_bf16(af[i], bfr[j],
                                                                    acc[i][j], 0, 0, 0);
        __syncthreads();
    }
    int rbase = (lane >> 4) << 2;
#pragma unroll
    for (int i = 0; i < 4; ++i) {
#pragma unroll
        for (int j = 0; j < 4; ++j) {
            int col = n0 + wc + j * 16 + lr;
            float bv = bias[col];
#pragma unroll
            for (int r = 0; r < 4; ++r) {
                int row = m0 + wr + i * 16 + rbase + r;
                float v = acc[i][j][r] + bv;
                if (SILU) v = v / (1.f + __expf(-v));
                if (OUT_BF16)
                    ((unsigned short*)Cout)[(size_t)row * N + col] = f2bf(v);
                else
                    ((float*)Cout)[(size_t)row * N + col] = v;
            }
        }
    }
}

// ---------------- LayerNorm (+ optional bf16 copy of output) ---------------
__global__ __launch_bounds__(256) void ln_kernel(const float* __restrict__ x1,
                                                 const float* __restrict__ x2,
                                                 const float* __restrict__ cbias,
                                                 const float* __restrict__ g,
                                                 const float* __restrict__ bt,
                                                 float* __restrict__ out,
                                                 unsigned short* __restrict__ out_bf) {
    int lane = threadIdx.x & 63;
    size_t row = ((size_t)blockIdx.x << 2) + (threadIdx.x >> 6);
    int c = lane << 2;
    size_t off = row * DMODEL + c;
    float4 x = *(const float4*)(x1 + off);
    float4 y = *(const float4*)(x2 + off);
    x.x += y.x; x.y += y.y; x.z += y.z; x.w += y.w;
    if (cbias) {
        float4 cb = *(const float4*)(cbias + c);
        x.x += cb.x; x.y += cb.y; x.z += cb.z; x.w += cb.w;
    }
    float s = x.x + x.y + x.z + x.w;
    float sq = x.x * x.x + x.y * x.y + x.z * x.z + x.w * x.w;
#pragma unroll
    for (int m = 32; m; m >>= 1) {
        s += __shfl_xor(s, m);
        sq += __shfl_xor(sq, m);
    }
    float mean = s * (1.f / 256.f);
    float var = sq * (1.f / 256.f) - mean * mean;
    float rinv = rsqrtf(var + 1e-5f);
    float4 gg = *(const float4*)(g + c);
    float4 bb = *(const float4*)(bt + c);
    float4 o;
    o.x = (x.x - mean) * rinv * gg.x + bb.x;
    o.y = (x.y - mean) * rinv * gg.y + bb.y;
    o.z = (x.z - mean) * rinv * gg.z + bb.z;
    o.w = (x.w - mean) * rinv * gg.w + bb.w;
    *(float4*)(out + off) = o;
    if (out_bf) {
        ushort4v ob;
        ob.x = f2bf(o.x); ob.y = f2bf(o.y); ob.z = f2bf(o.z); ob.w = f2bf(o.w);
        *(ushort4v*)(out_bf + off) = ob;
    }
}

// ---------------------------------------------------------------------------
extern "C" void kernel_launch(void* const* d_in, const int* in_sizes, int n_in,
                              void* d_out, int out_size, void* d_ws, size_t ws_size,
                              hipStream_t stream) {
    const float* obs     = (const float*)d_in[0];
    const float* filters = (const float*)d_in[1];
    const float* W_in    = (const float*)d_in[2];
    const float* b_in    = (const float*)d_in[3];
    const float* Mpos    = (const float*)d_in[4];
    const float* Mneg    = (const float*)d_in[5];
    const float* MdirW   = (const float*)d_in[6];
    const float* Mdirb   = (const float*)d_in[7];
    const float* ln1g    = (const float*)d_in[8];
    const float* ln1b    = (const float*)d_in[9];
    const float* W1      = (const float*)d_in[10];
    const float* b1      = (const float*)d_in[11];
    const float* W2      = (const float*)d_in[12];
    const float* b2      = (const float*)d_in[13];
    const float* ln2g    = (const float*)d_in[14];
    const float* ln2b    = (const float*)d_in[15];
    const float* W_out   = (const float*)d_in[16];
    const float* b_out   = (const float*)d_in[17];
    float* out = (float*)d_out;

    // ---- workspace (floats), liveness-aliased ----
    float* p = (float*)d_ws;
    float* h   = p; p += 4194304;       // (B,L,D)
    float* C1  = p; p += 8392704;       // XfT -> Wf -> spec (first 4.2M) | bf16 tail
    float* C2  = p; p += 8392704;       // Xf -> WfT -> hln
    float* Ffp = p; p += 65568;
    float* Ffn = p; p += 65568;
    float* Fpk = p; p += 131136;
    float* fng = p; p += 32768;
    float* big = p;
    size_t fixed_f = (size_t)(big - (float*)d_ws);
    size_t avail_f = (ws_size / 4 > fixed_f) ? ws_size / 4 - fixed_f : 0;

    int chunk = CHUNKMAX;                              // Gb: chunk*65536 uints
    while (chunk > 8 && (size_t)chunk * 65536 > avail_f) chunk >>= 1;
    int RB = 16384;                                    // MLP row block
    while (RB > 128 && (size_t)RB * 512 > avail_f) RB >>= 1;   // mid_bf = RB*512 f32

    float* sT  = big;
    unsigned int* Gb = (unsigned int*)big;
    unsigned short* mid_bf = (unsigned short*)big;
    // bf16 side buffers live in C1's tail (spec only uses C1[0 .. 4.2M))
    unsigned short* hln_bf = (unsigned short*)(C1 + 4194304);   // 2,097,152 f32
    unsigned short* W1T    = (unsigned short*)(C1 + 6291456);   // 131,072 f32
    unsigned short* W2T    = (unsigned short*)(C1 + 6422528);   // 131,072 f32

    dim3 tb(32, 8);

    // filter prep
    fneg_kernel<<<128, 256, 0, stream>>>(filters, fng);
    fft_fwd<<<NK, 256, 0, stream>>>(filters, (float2*)Ffp);
    fft_fwd<<<NK, 256, 0, stream>>>(fng, (float2*)Ffn);
    pack_kernel<<<(NBINS * 32 + 255) / 256, 256, 0, stream>>>((float2*)Ffp, (float2*)Ffn,
                                                              (float2*)Fpk);
    // input projection: h = obs @ W_in + b_in
    sgemm<128, 64, 0><<<dim3(4, 128), 256, 0, stream>>>(obs, W_in, b_in, h, 256, 128);

    for (int i = 0; i < 2; ++i) {
        const float* Mp = Mpos + (size_t)i * 1048576;
        const float* Mn = Mneg + (size_t)i * 1048576;
        const float* Md = MdirW + (size_t)i * 65536;

        // h (B,L,D) -> sT (B,D,L); packed FFT -> C1; -> C2 = Xf (B,2049,D)
        transpose_f<<<dim3(8, 64, 8), tb, 0, stream>>>(h, sT, LSEQ, DMODEL);
        fft_fwd2<<<1024, 256, 0, stream>>>(sT, (float2*)C1);
        transpose_f2<<<dim3(65, 8, 8), tb, 0, stream>>>((float2*)C1, (float2*)C2,
                                                        DMODEL, NBINS);
        // chunked G build (bf16) + apply (Wf -> C1)
        for (int w0 = 0; w0 < NBINS; w0 += chunk) {
            int CB = (NBINS - w0 < chunk) ? (NBINS - w0) : chunk;
            build_g<<<dim3(256, NSPLIT), 256, 0, stream>>>(Mp, Mn, Md, (float2*)Fpk,
                                                           Gb, w0, CB);
            apply_g<<<dim3(CB, 2), 256, 0, stream>>>((float2*)C2, Gb,
                                                     (float2*)C1, w0);
        }
        // Wf (C1) -> WfT (C2); packed iFFT -> sT; -> spec (C1[0..4.2M))
        transpose_f2<<<dim3(8, 65, 8), tb, 0, stream>>>((float2*)C1, (float2*)C2,
                                                        NBINS, DMODEL);
        fft_inv2<<<1024, 256, 0, stream>>>((float2*)C2, sT);
        transpose_f<<<dim3(64, 8, 8), tb, 0, stream>>>(sT, C1, DMODEL, LSEQ);

        float* spec = C1;   // (B,L,D)
        float* hln  = C2;   // (B,L,D)

        // LN1: hln = LN(h + spec + Mdir_b); also write bf16 copy
        ln_kernel<<<4096, 256, 0, stream>>>(h, spec, Mdirb + i * 256, ln1g + i * 256,
                                            ln1b + i * 256, hln, hln_bf);
        // weights -> bf16 transposed
        transpose_cvt<<<dim3(32, 8), tb, 0, stream>>>(W1 + (size_t)i * 262144, W1T,
                                                      256, 1024);
        transpose_cvt<<<dim3(8, 32), tb, 0, stream>>>(W2 + (size_t)i * 262144, W2T,
                                                      1024, 256);
        // MLP (bf16 MFMA): mid = silu(hln@W1+b1) [bf16]; mlpout = mid@W2+b2 [f32]
        for (int r0 = 0; r0 < MROWS; r0 += RB) {
            int rb = (MROWS - r0 < RB) ? (MROWS - r0) : RB;
            gemm_bf16<1, 1><<<dim3(8, rb / 128), 256, 0, stream>>>(
                hln_bf + (size_t)r0 * 256, W1T, b1 + i * 1024, mid_bf, 1024, 256);
            gemm_bf16<0, 0><<<dim3(2, rb / 128), 256, 0, stream>>>(
                mid_bf, W2T, b2 + i * 256, spec + (size_t)r0 * 256, 256, 1024);
        }
        // LN2: h = LN(hln + mlpout)
        ln_kernel<<<4096, 256, 0, stream>>>(hln, spec, nullptr, ln2g + i * 256,
                                            ln2b + i * 256, h, nullptr);
    }
    // output projection
    sgemm<64, 32, 0><<<dim3(1, 256), 256, 0, stream>>>(h, W_out, b_out, out, 32, 256);
}